// Round 14
// baseline (156.361 us; speedup 1.0000x reference)
//
#include <hip/hip_runtime.h>
#include <cstdint>
#include <type_traits>

#define SEQ 2048
#define NTOK 4096   // B*S = 2*2048

typedef unsigned short u16;
typedef __attribute__((ext_vector_type(8))) short bf16x8;
typedef __attribute__((ext_vector_type(4))) short bf16x4;
typedef __attribute__((ext_vector_type(4))) float f32x4;

// 0.125 (1/sqrt(64)) * log2(e): scores scaled into exp2 domain
#define C_SC 0.18033688f

#if __has_builtin(__builtin_amdgcn_exp2f)
#define EXP2F __builtin_amdgcn_exp2f     // raw v_exp_f32, no OCML fixup
#else
#define EXP2F __builtin_exp2f
#endif

__device__ __forceinline__ u16 f2bf(float f) {
  union { float f; uint32_t i; } c; c.f = f;
  uint32_t r = c.i + 0x7FFF + ((c.i >> 16) & 1);   // RNE, finite inputs
  return (u16)(r >> 16);
}
__device__ __forceinline__ void gload_lds16(const void* g, void* l) {
  __builtin_amdgcn_global_load_lds(
      (const __attribute__((address_space(1))) uint32_t*)g,
      (__attribute__((address_space(3))) uint32_t*)l, 16, 0, 0);
}
// hardware 4-elem stride-16 transpose read (gfx950): lane receives column
// ((addr&127)>>3) of the 4x16 bf16 subtile containing addr; elem j = row j.
// Caller must fence with s_waitcnt lgkmcnt + sched_barrier before use (rule #18).
__device__ __forceinline__ bf16x4 tr_read_b16(const u16* p) {
  bf16x4 d;
  auto a = (const __attribute__((address_space(3))) u16*)p;
  asm volatile("ds_read_b64_tr_b16 %0, %1" : "=v"(d) : "v"(a));
  return d;
}

// ---------- prep: all f32->bf16 casts + bias pack in ONE launch ----------
__global__ void prep_kernel(const float* __restrict__ x,
                            const float* __restrict__ wq, const float* __restrict__ wk,
                            const float* __restrict__ wv, const float* __restrict__ wo,
                            const float* __restrict__ qb, const float* __restrict__ kb,
                            const float* __restrict__ vb,
                            u16* __restrict__ Xb, u16* __restrict__ Wqkv,
                            u16* __restrict__ Wo, float* __restrict__ biasq) {
  int gid = blockIdx.x;
  if (gid < 8192) {
    const float* s; u16* d; int i;
    if (gid < 4096)      { s = x;  d = Xb;                  i = gid * 256 + threadIdx.x; }
    else if (gid < 5120) { s = wq; d = Wqkv;                i = (gid - 4096) * 256 + threadIdx.x; }
    else if (gid < 6144) { s = wk; d = Wqkv + 1024 * 1024;  i = (gid - 5120) * 256 + threadIdx.x; }
    else if (gid < 7168) { s = wv; d = Wqkv + 2048 * 1024;  i = (gid - 6144) * 256 + threadIdx.x; }
    else                 { s = wo; d = Wo;                  i = (gid - 7168) * 256 + threadIdx.x; }
    float4 v = ((const float4*)s)[i];
    uint2 o;
    o.x = (uint)f2bf(v.x) | ((uint)f2bf(v.y) << 16);
    o.y = (uint)f2bf(v.z) | ((uint)f2bf(v.w) << 16);
    ((uint2*)d)[i] = o;
  } else {
    int i = (gid - 8192) * 256 + threadIdx.x;
    if (i < 1024) biasq[i] = qb[i];
    else if (i < 2048) biasq[i] = kb[i - 1024];
    else if (i < 3072) biasq[i] = vb[i - 2048];
  }
}

// ---------- GEMM: 128x128 tile, BK=32, 3-stage ring + counted vmcnt (T4) ----------
// Per step i: vmcnt(4) [own stage(i) landed; stage(i+1) stays in flight] ->
// raw s_barrier + compiler fence [all waves' stage(i) landed; all reads of the
// to-be-overwritten buffer retired] -> stage(i+2) into buf (i-1)%3 -> compute(i).
// Each stage has 2 full steps to cover HBM/L2 latency (vs the old barrier-drain
// which exposed it every step). XOR-swizzled LDS (pre-swizzled src, rule #21).
template <typename OT, bool ROPE>
__global__ __launch_bounds__(256) void gemm_bt(
    const u16* __restrict__ A, const u16* __restrict__ Bt,
    const float* __restrict__ bias, OT* __restrict__ C,
    int M, int N, int K, const float* __restrict__ freqs)
{
  __shared__ alignas(16) u16 As[3][128 * 32];
  __shared__ alignas(16) u16 Bs[3][128 * 32];
  const int t = threadIdx.x, w = t >> 6, l = t & 63;
  const int lo = l & 15, hi = l >> 4;
  const int nwg = gridDim.x * gridDim.y;
  const int f = blockIdx.y * gridDim.x + blockIdx.x;
  const int f2 = (f & 7) * (nwg >> 3) + (f >> 3);
  const int m0 = (f2 % gridDim.x) * 128, n0 = (f2 / gridDim.x) * 128;
  const int wm = w >> 1, wn = w & 1;
  f32x4 acc[4][4] = {};
  const int srow = t >> 2;                        // 0..63
  const int scol = ((t & 3) ^ (srow & 3)) << 3;   // pre-swizzled col (elems)
  const u16* ga = A + (size_t)(m0 + srow) * K + scol;
  const u16* gb = Bt + (size_t)(n0 + srow) * K + scol;
  const int sw = (lo & 3) << 4;
  auto stage = [&](int buf, int kt) {
    char* dA = (char*)&As[buf][0] + t * 16;
    char* dB = (char*)&Bs[buf][0] + t * 16;
    gload_lds16(ga + kt, dA);
    gload_lds16(ga + (size_t)64 * K + kt, dA + 4096);
    gload_lds16(gb + kt, dB);
    gload_lds16(gb + (size_t)64 * K + kt, dB + 4096);
  };
  auto compute = [&](int buf) {
    const char* as = (const char*)&As[buf][0];
    const char* bs = (const char*)&Bs[buf][0];
    bf16x8 af[4], bfr[4];
#pragma unroll
    for (int mi = 0; mi < 4; ++mi)
      af[mi] = *(const bf16x8*)(as + (wm * 64 + mi * 16 + lo) * 64 + ((hi << 4) ^ sw));
#pragma unroll
    for (int ni = 0; ni < 4; ++ni)
      bfr[ni] = *(const bf16x8*)(bs + (wn * 64 + ni * 16 + lo) * 64 + ((hi << 4) ^ sw));
#pragma unroll
    for (int mi = 0; mi < 4; ++mi)
#pragma unroll
      for (int ni = 0; ni < 4; ++ni)
        acc[mi][ni] = __builtin_amdgcn_mfma_f32_16x16x32_bf16(af[mi], bfr[ni], acc[mi][ni], 0, 0, 0);
  };

  const int NS = K >> 5;             // K/32 steps (NS >= 2 for all our shapes)
  stage(0, 0);
  stage(1, 32);
  for (int i = 0; i < NS - 2; ++i) {
    asm volatile("s_waitcnt vmcnt(4)" ::: "memory");   // stage(i) landed (own wave)
    __builtin_amdgcn_s_barrier();                      // all waves: stage(i) landed,
    asm volatile("" ::: "memory");                     // prior reads retired; fence loads
    stage((i + 2) % 3, (i + 2) * 32);                  // overwrite buf read at step i-1
    compute(i % 3);
  }
  asm volatile("s_waitcnt vmcnt(4)" ::: "memory");     // stage(NS-2) landed
  __builtin_amdgcn_s_barrier();
  asm volatile("" ::: "memory");
  compute((NS - 2) % 3);
  asm volatile("s_waitcnt vmcnt(0)" ::: "memory");     // stage(NS-1) landed
  __builtin_amdgcn_s_barrier();
  asm volatile("" ::: "memory");
  compute((NS - 1) % 3);

  const bool do_rope = ROPE && (n0 < 2048);
  const float2* fc = (const float2*)freqs;
#pragma unroll
  for (int mi = 0; mi < 4; ++mi)
#pragma unroll
    for (int ni = 0; ni < 4; ++ni) {
      int col = n0 + wn * 64 + ni * 16 + lo;
      float b = bias[col];
      int pr = (col >> 1) & 31;
#pragma unroll
      for (int r = 0; r < 4; ++r) {
        int row = m0 + wm * 64 + mi * 16 + hi * 4 + r;
        float v = acc[mi][ni][r] + b;
        if (do_rope) {
          float pv = __shfl_xor(v, 1, 64);
          float2 fq = fc[(row & (SEQ - 1)) * 32 + pr];
          float fs = (col & 1) ? fq.y : -fq.y;
          v = v * fq.x + pv * fs;
        }
        if constexpr (std::is_same<OT, u16>::value)
          C[(size_t)row * N + col] = f2bf(v);
        else
          C[(size_t)row * N + col] = v;
      }
    }
}

// ---------- flash attention (R8 VERBATIM — frozen passing version) ----------
// grid (S/64, B*NH), XCD-swizzled. 4 waves; wave w owns 16 q rows. KV tile 64.
// K double-buffered (prefetch i+1); V SINGLE-buffered (staged in-loop, own-wave
// vmcnt(2) + raw s_barrier). LDS 32 KB.
__global__ __launch_bounds__(256, 4) void attn_kernel(const u16* __restrict__ QKV, u16* __restrict__ Y) {
  const int fblk = blockIdx.y * 32 + blockIdx.x;
  const int f2 = (fblk & 7) * 128 + (fblk >> 3);   // bijective, 1024 % 8 == 0
  const int qt = f2 & 31, bh = f2 >> 5;
  const int b = bh >> 4, h = bh & 15;
  const int t = threadIdx.x, w = t >> 6, l = t & 63;
  const int lo = l & 15, hi = l >> 4;
  const int q0 = qt * 64;
  const int NT = SEQ / 64;
  __shared__ alignas(128) u16 Ks[2][64 * 64];   // swizzled [row][d], double-buffered
  __shared__ alignas(128) u16 Vs[64 * 64];      // subtiled, SINGLE buffer
  __shared__ alignas(128) u16 Pl[4][1024];      // per-wave P^T: off(k,q)=(k>>2)*64+(k&3)*16+q

  const u16* Qrow = QKV + (size_t)(b * SEQ + q0 + w * 16 + lo) * 3072 + h * 64;
  bf16x8 qf0 = *(const bf16x8*)(Qrow + hi * 8);
  bf16x8 qf1 = *(const bf16x8*)(Qrow + 32 + hi * 8);

  const short one_bf = (short)0x3F80;
  const bf16x8 ones = {one_bf, one_bf, one_bf, one_bf, one_bf, one_bf, one_bf, one_bf};

  f32x4 acc[4] = {};
  f32x4 accl = {};
  float mr[4];
#pragma unroll
  for (int r = 0; r < 4; ++r) mr[r] = -INFINITY;

  // staging sources (per-thread chunks)
  const u16* Kg = QKV + (size_t)b * SEQ * 3072 + 1024 + h * 64;
  const u16* Vg = QKV + (size_t)b * SEQ * 3072 + 2048 + h * 64;
  const int kr = t >> 3;
  const int ksc = (((t & 7) ^ (kr & 7)) << 3);
  const u16* pK1 = Kg + (size_t)kr * 3072 + ksc;
  const int vk = ((t >> 5) << 2) | ((t >> 1) & 3);
  const int vd = (((t >> 3) & 3) << 4) | ((t & 1) << 3);
  const u16* pV1 = Vg + (size_t)vk * 3072 + vd;

  const int sw = (lo & 7) << 4;
  u16* plw = &Pl[w][0];
  const int wbase = ((lo >> 2) << 6) + ((lo & 3) << 4) + (hi << 2);  // P^T write (u16 idx)
  const u16* pt = plw + lo * 4;                                      // P^T tr-read base

  auto stageK = [&](int buf, int it2) {
    const size_t koff = (size_t)it2 * 64 * 3072;
    char* dK = (char*)&Ks[buf][0] + t * 16;
    gload_lds16(pK1 + koff, dK);
    gload_lds16(pK1 + koff + (size_t)32 * 3072, dK + 4096);
  };
  auto stageV = [&](int it2) {
    const size_t koff = (size_t)it2 * 64 * 3072;
    char* dV = (char*)Vs + t * 16;
    gload_lds16(pV1 + koff, dV);
    gload_lds16(pV1 + koff + (size_t)32 * 3072, dV + 4096);
  };

  stageK(0, 0);
  int cur = 0;
  for (int it = 0; it < NT; ++it) {
    __syncthreads();                 // PV(i-1) done everywhere; K(cur) landed
    stageV(it);                      // oldest 2 VMEM ops -> vmcnt(2) targets these
    if (it + 1 < NT) stageK(cur ^ 1, it + 1);

    // QK^T raw scores: S[16q][64k] per wave
    const char* ksb = (const char*)&Ks[cur][0];
    f32x4 sr[4];
    __builtin_amdgcn_s_setprio(1);
#pragma unroll
    for (int fk = 0; fk < 4; ++fk) {
      const char* krow = ksb + (fk * 16 + lo) * 128;
      bf16x8 kb0 = *(const bf16x8*)(krow + ((hi << 4) ^ sw));
      bf16x8 kb1 = *(const bf16x8*)(krow + ((64 + (hi << 4)) ^ sw));
      f32x4 s4 = {};
      s4 = __builtin_amdgcn_mfma_f32_16x16x32_bf16(qf0, kb0, s4, 0, 0, 0);
      sr[fk] = __builtin_amdgcn_mfma_f32_16x16x32_bf16(qf1, kb1, s4, 0, 0, 0);
    }
    __builtin_amdgcn_s_setprio(0);

    // per-lane tile max (scaled into exp2 domain)
    float tm[4];
#pragma unroll
    for (int r = 0; r < 4; ++r)
      tm[r] = fmaxf(fmaxf(sr[0][r], sr[1][r]), fmaxf(sr[2][r], sr[3][r])) * C_SC;

    // defer-max: rescale only if some row grew past mr + 8
    bool ok = (tm[0] <= mr[0] + 8.f) & (tm[1] <= mr[1] + 8.f)
            & (tm[2] <= mr[2] + 8.f) & (tm[3] <= mr[3] + 8.f);
    if (!__all(ok ? 1 : 0)) {
#pragma unroll
      for (int m = 1; m <= 8; m <<= 1)
#pragma unroll
        for (int r = 0; r < 4; ++r)
          tm[r] = fmaxf(tm[r], __shfl_xor(tm[r], m, 64));
#pragma unroll
      for (int r = 0; r < 4; ++r) {
        float mn = fmaxf(mr[r], tm[r]);
        float corr = EXP2F(mr[r] - mn);
        mr[r] = mn;
        acc[0][r] *= corr; acc[1][r] *= corr; acc[2][r] *= corr; acc[3][r] *= corr;
        accl[r] *= corr;
      }
    }

    // P = exp2(s*c - m), pack pairs via cvt_pk, store to P^T (b64 writes)
    float nm0 = -mr[0], nm1 = -mr[1], nm2 = -mr[2], nm3 = -mr[3];
#pragma unroll
    for (int fk = 0; fk < 4; ++fk) {
      float p0 = EXP2F(fmaf(sr[fk][0], C_SC, nm0));
      float p1 = EXP2F(fmaf(sr[fk][1], C_SC, nm1));
      float p2 = EXP2F(fmaf(sr[fk][2], C_SC, nm2));
      float p3 = EXP2F(fmaf(sr[fk][3], C_SC, nm3));
      uint2 pk;
      asm("v_cvt_pk_bf16_f32 %0, %1, %2" : "=v"(pk.x) : "v"(p0), "v"(p1));
      asm("v_cvt_pk_bf16_f32 %0, %1, %2" : "=v"(pk.y) : "v"(p2), "v"(p3));
      *(uint2*)&plw[wbase + fk * 256] = pk;
    }
    asm volatile("" ::: "memory");   // P stores stay above the barrier/tr-reads

    // V ready: wait OWN V loads (K(i+1) stays in flight), then cross-wave barrier
    if (it + 1 < NT) { asm volatile("s_waitcnt vmcnt(2)" ::: "memory"); }
    else             { asm volatile("s_waitcnt vmcnt(0)" ::: "memory"); }
    __builtin_amdgcn_s_barrier();

    // PV: issue ALL tr-reads (P + V, both kk halves), counted lgkm waits
    const u16* vbase = &Vs[0] + hi * 512 + lo * 4;
    bf16x4 a0[2], a1[2], ta[2][4], tb[2][4];
#pragma unroll
    for (int kk = 0; kk < 2; ++kk) {
      a0[kk] = tr_read_b16(pt + (kk * 8 + hi * 2) * 64);
      a1[kk] = tr_read_b16(pt + (kk * 8 + hi * 2) * 64 + 64);
#pragma unroll
      for (int fd = 0; fd < 4; ++fd) {
        const u16* p0 = vbase + kk * 2048 + fd * 64;
        ta[kk][fd] = tr_read_b16(p0);
        tb[kk][fd] = tr_read_b16(p0 + 256);
      }
    }
    asm volatile("s_waitcnt lgkmcnt(10)" ::: "memory");   // kk0's 10 reads done
    __builtin_amdgcn_sched_barrier(0);
    __builtin_amdgcn_s_setprio(1);
    {
      bf16x8 pa = __builtin_shufflevector(a0[0], a1[0], 0, 1, 2, 3, 4, 5, 6, 7);
      accl = __builtin_amdgcn_mfma_f32_16x16x32_bf16(pa, ones, accl, 0, 0, 0);
#pragma unroll
      for (int fd = 0; fd < 4; ++fd) {
        bf16x8 vb = __builtin_shufflevector(ta[0][fd], tb[0][fd], 0, 1, 2, 3, 4, 5, 6, 7);
        acc[fd] = __builtin_amdgcn_mfma_f32_16x16x32_bf16(pa, vb, acc[fd], 0, 0, 0);
      }
    }
    __builtin_amdgcn_s_setprio(0);
    asm volatile("s_waitcnt lgkmcnt(0)" ::: "memory");
    __builtin_amdgcn_sched_barrier(0);
    __builtin_amdgcn_s_setprio(1);
    {
      bf16x8 pa = __builtin_shufflevector(a0[1], a1[1], 0, 1, 2, 3, 4, 5, 6, 7);
      accl = __builtin_amdgcn_mfma_f32_16x16x32_bf16(pa, ones, accl, 0, 0, 0);
#pragma unroll
      for (int fd = 0; fd < 4; ++fd) {
        bf16x8 vb = __builtin_shufflevector(ta[1][fd], tb[1][fd], 0, 1, 2, 3, 4, 5, 6, 7);
        acc[fd] = __builtin_amdgcn_mfma_f32_16x16x32_bf16(pa, vb, acc[fd], 0, 0, 0);
      }
    }
    __builtin_amdgcn_s_setprio(0);
    cur ^= 1;
  }

  // epilogue: O / l -> Y bf16
  float rinv[4];
#pragma unroll
  for (int r = 0; r < 4; ++r) rinv[r] = __builtin_amdgcn_rcpf(accl[r]);
#pragma unroll
  for (int fd = 0; fd < 4; ++fd)
#pragma unroll
    for (int r = 0; r < 4; ++r) {
      int row = q0 + w * 16 + hi * 4 + r;
      int col = h * 64 + fd * 16 + lo;
      Y[(size_t)(b * SEQ + row) * 1024 + col] = f2bf(acc[fd][r] * rinv[r]);
    }
}

extern "C" void kernel_launch(void* const* d_in, const int* in_sizes, int n_in,
                              void* d_out, int out_size, void* d_ws, size_t ws_size,
                              hipStream_t stream) {
  const float* x     = (const float*)d_in[0];
  const float* freqs = (const float*)d_in[1];
  const float* wq_w  = (const float*)d_in[2];
  const float* wq_b  = (const float*)d_in[3];
  const float* wk_w  = (const float*)d_in[4];
  const float* wk_b  = (const float*)d_in[5];
  const float* wv_w  = (const float*)d_in[6];
  const float* wv_b  = (const float*)d_in[7];
  const float* wo_w  = (const float*)d_in[8];
  const float* wo_b  = (const float*)d_in[9];

  char* ws = (char*)d_ws;
  u16*   Xb    = (u16*)(ws);                       //  8 MB  (4096x1024 bf16)
  u16*   Wqkv  = (u16*)(ws + 8388608);             //  6 MB  (3072x1024 bf16)
  u16*   Wo    = (u16*)(ws + 14680064);            //  2 MB  (1024x1024 bf16)
  float* biasq = (float*)(ws + 16777216);          // 12 KB  (3072 f32)
  u16*   QKV   = (u16*)(ws + 16789504);            // 24 MB  (4096x3072 bf16)
  u16*   Yb    = (u16*)(ws + 41955328);            //  8 MB  (4096x1024 bf16)

  prep_kernel<<<8204, 256, 0, stream>>>(x, wq_w, wk_w, wv_w, wo_w, wq_b, wk_b, wv_b,
                                        Xb, Wqkv, Wo, biasq);
  // QKV projection with fused RoPE on Q,K columns
  gemm_bt<u16, true><<<dim3(32, 24), 256, 0, stream>>>(Xb, Wqkv, biasq, QKV, NTOK, 3072, 1024, freqs);
  // attention
  attn_kernel<<<dim3(SEQ / 64, 32), 256, 0, stream>>>(QKV, Yb);
  // output projection -> f32 d_out
  gemm_bt<float, false><<<dim3(32, 8), 256, 0, stream>>>(Yb, Wo, wo_b, (float*)d_out, NTOK, 1024, 1024, nullptr);
}

// Round 15
// 148.322 us; speedup vs baseline: 1.0542x; 1.0542x over previous
//
#include <hip/hip_runtime.h>
#include <cstdint>
#include <type_traits>

#define SEQ 2048
#define NTOK 4096   // B*S = 2*2048

typedef unsigned short u16;
typedef __attribute__((ext_vector_type(8))) short bf16x8;
typedef __attribute__((ext_vector_type(4))) short bf16x4;
typedef __attribute__((ext_vector_type(4))) float f32x4;

// 0.125 (1/sqrt(64)) * log2(e): scores scaled into exp2 domain
#define C_SC 0.18033688f

#if __has_builtin(__builtin_amdgcn_exp2f)
#define EXP2F __builtin_amdgcn_exp2f     // raw v_exp_f32, no OCML fixup
#else
#define EXP2F __builtin_exp2f
#endif

__device__ __forceinline__ u16 f2bf(float f) {
  union { float f; uint32_t i; } c; c.f = f;
  uint32_t r = c.i + 0x7FFF + ((c.i >> 16) & 1);   // RNE, finite inputs
  return (u16)(r >> 16);
}
__device__ __forceinline__ void gload_lds16(const void* g, void* l) {
  __builtin_amdgcn_global_load_lds(
      (const __attribute__((address_space(1))) uint32_t*)g,
      (__attribute__((address_space(3))) uint32_t*)l, 16, 0, 0);
}
// hardware 4-elem stride-16 transpose read (gfx950): lane receives column
// ((addr&127)>>3) of the 4x16 bf16 subtile containing addr; elem j = row j.
// Caller must fence with s_waitcnt lgkmcnt + sched_barrier before use (rule #18).
__device__ __forceinline__ bf16x4 tr_read_b16(const u16* p) {
  bf16x4 d;
  auto a = (const __attribute__((address_space(3))) u16*)p;
  asm volatile("ds_read_b64_tr_b16 %0, %1" : "=v"(d) : "v"(a));
  return d;
}

// ---------- prep: all f32->bf16 casts + bias pack in ONE launch ----------
__global__ void prep_kernel(const float* __restrict__ x,
                            const float* __restrict__ wq, const float* __restrict__ wk,
                            const float* __restrict__ wv, const float* __restrict__ wo,
                            const float* __restrict__ qb, const float* __restrict__ kb,
                            const float* __restrict__ vb,
                            u16* __restrict__ Xb, u16* __restrict__ Wqkv,
                            u16* __restrict__ Wo, float* __restrict__ biasq) {
  int gid = blockIdx.x;
  if (gid < 8192) {
    const float* s; u16* d; int i;
    if (gid < 4096)      { s = x;  d = Xb;                  i = gid * 256 + threadIdx.x; }
    else if (gid < 5120) { s = wq; d = Wqkv;                i = (gid - 4096) * 256 + threadIdx.x; }
    else if (gid < 6144) { s = wk; d = Wqkv + 1024 * 1024;  i = (gid - 5120) * 256 + threadIdx.x; }
    else if (gid < 7168) { s = wv; d = Wqkv + 2048 * 1024;  i = (gid - 6144) * 256 + threadIdx.x; }
    else                 { s = wo; d = Wo;                  i = (gid - 7168) * 256 + threadIdx.x; }
    float4 v = ((const float4*)s)[i];
    uint2 o;
    o.x = (uint)f2bf(v.x) | ((uint)f2bf(v.y) << 16);
    o.y = (uint)f2bf(v.z) | ((uint)f2bf(v.w) << 16);
    ((uint2*)d)[i] = o;
  } else {
    int i = (gid - 8192) * 256 + threadIdx.x;
    if (i < 1024) biasq[i] = qb[i];
    else if (i < 2048) biasq[i] = kb[i - 1024];
    else if (i < 3072) biasq[i] = vb[i - 2048];
  }
}

// ---------- GEMM: BMx128 tile, BK=32, 2-phase dbuf (R13 structure), +fused RoPE ----------
// BM template param (128 or 64). BM=64 doubles block count for small-N GEMMs
// (GEMM2 was 1 block/CU -> zero inter-block latency overlap; R14 lesson:
// blocks/CU is the latency-hiding lever, not loop restructuring).
template <typename OT, bool ROPE, int BM>
__global__ __launch_bounds__(256) void gemm_bt(
    const u16* __restrict__ A, const u16* __restrict__ Bt,
    const float* __restrict__ bias, OT* __restrict__ C,
    int M, int N, int K, const float* __restrict__ freqs)
{
  constexpr int MI = BM / 32;        // 16-row frags per wave (wave owns BM/2 rows)
  __shared__ alignas(16) u16 As[2][BM * 32];
  __shared__ alignas(16) u16 Bs[2][128 * 32];
  const int t = threadIdx.x, w = t >> 6, l = t & 63;
  const int lo = l & 15, hi = l >> 4;
  const int nwg = gridDim.x * gridDim.y;
  const int f = blockIdx.y * gridDim.x + blockIdx.x;
  const int f2 = (f & 7) * (nwg >> 3) + (f >> 3);
  const int m0 = (f2 % gridDim.x) * BM, n0 = (f2 / gridDim.x) * 128;
  const int wm = w >> 1, wn = w & 1;
  f32x4 acc[MI][4] = {};
  const int srow = t >> 2;                        // 0..63
  const int scol = ((t & 3) ^ (srow & 3)) << 3;   // pre-swizzled col (elems)
  const u16* ga = A + (size_t)(m0 + srow) * K + scol;
  const u16* gb = Bt + (size_t)(n0 + srow) * K + scol;
  const int sw = (lo & 3) << 4;
  auto stage = [&](int buf, int kt) {
    char* dA = (char*)&As[buf][0] + t * 16;
    char* dB = (char*)&Bs[buf][0] + t * 16;
#pragma unroll
    for (int j = 0; j < BM / 64; ++j)
      gload_lds16(ga + (size_t)(64 * j) * K + kt, dA + j * 4096);
    gload_lds16(gb + kt, dB);
    gload_lds16(gb + (size_t)64 * K + kt, dB + 4096);
  };
  stage(0, 0);
  int buf = 0;
  for (int kt = 0; kt < K; kt += 32, buf ^= 1) {
    __syncthreads();
    if (kt + 32 < K) stage(buf ^ 1, kt + 32);
    const char* as = (const char*)&As[buf][0];
    const char* bs = (const char*)&Bs[buf][0];
    bf16x8 af[MI], bfr[4];
#pragma unroll
    for (int mi = 0; mi < MI; ++mi)
      af[mi] = *(const bf16x8*)(as + (wm * (BM / 2) + mi * 16 + lo) * 64 + ((hi << 4) ^ sw));
#pragma unroll
    for (int ni = 0; ni < 4; ++ni)
      bfr[ni] = *(const bf16x8*)(bs + (wn * 64 + ni * 16 + lo) * 64 + ((hi << 4) ^ sw));
#pragma unroll
    for (int mi = 0; mi < MI; ++mi)
#pragma unroll
      for (int ni = 0; ni < 4; ++ni)
        acc[mi][ni] = __builtin_amdgcn_mfma_f32_16x16x32_bf16(af[mi], bfr[ni], acc[mi][ni], 0, 0, 0);
  }
  const bool do_rope = ROPE && (n0 < 2048);
  const float2* fc = (const float2*)freqs;
#pragma unroll
  for (int mi = 0; mi < MI; ++mi)
#pragma unroll
    for (int ni = 0; ni < 4; ++ni) {
      int col = n0 + wn * 64 + ni * 16 + lo;
      float b = bias[col];
      int pr = (col >> 1) & 31;
#pragma unroll
      for (int r = 0; r < 4; ++r) {
        int row = m0 + wm * (BM / 2) + mi * 16 + hi * 4 + r;
        float v = acc[mi][ni][r] + b;
        if (do_rope) {
          float pv = __shfl_xor(v, 1, 64);
          float2 fq = fc[(row & (SEQ - 1)) * 32 + pr];
          float fs = (col & 1) ? fq.y : -fq.y;
          v = v * fq.x + pv * fs;
        }
        if constexpr (std::is_same<OT, u16>::value)
          C[(size_t)row * N + col] = f2bf(v);
        else
          C[(size_t)row * N + col] = v;
      }
    }
}

// ---------- flash attention (R8 VERBATIM — frozen passing version) ----------
// grid (S/64, B*NH), XCD-swizzled. 4 waves; wave w owns 16 q rows. KV tile 64.
// K double-buffered (prefetch i+1); V SINGLE-buffered (staged in-loop, own-wave
// vmcnt(2) + raw s_barrier). LDS 32 KB.
__global__ __launch_bounds__(256, 4) void attn_kernel(const u16* __restrict__ QKV, u16* __restrict__ Y) {
  const int fblk = blockIdx.y * 32 + blockIdx.x;
  const int f2 = (fblk & 7) * 128 + (fblk >> 3);   // bijective, 1024 % 8 == 0
  const int qt = f2 & 31, bh = f2 >> 5;
  const int b = bh >> 4, h = bh & 15;
  const int t = threadIdx.x, w = t >> 6, l = t & 63;
  const int lo = l & 15, hi = l >> 4;
  const int q0 = qt * 64;
  const int NT = SEQ / 64;
  __shared__ alignas(128) u16 Ks[2][64 * 64];   // swizzled [row][d], double-buffered
  __shared__ alignas(128) u16 Vs[64 * 64];      // subtiled, SINGLE buffer
  __shared__ alignas(128) u16 Pl[4][1024];      // per-wave P^T: off(k,q)=(k>>2)*64+(k&3)*16+q

  const u16* Qrow = QKV + (size_t)(b * SEQ + q0 + w * 16 + lo) * 3072 + h * 64;
  bf16x8 qf0 = *(const bf16x8*)(Qrow + hi * 8);
  bf16x8 qf1 = *(const bf16x8*)(Qrow + 32 + hi * 8);

  const short one_bf = (short)0x3F80;
  const bf16x8 ones = {one_bf, one_bf, one_bf, one_bf, one_bf, one_bf, one_bf, one_bf};

  f32x4 acc[4] = {};
  f32x4 accl = {};
  float mr[4];
#pragma unroll
  for (int r = 0; r < 4; ++r) mr[r] = -INFINITY;

  // staging sources (per-thread chunks)
  const u16* Kg = QKV + (size_t)b * SEQ * 3072 + 1024 + h * 64;
  const u16* Vg = QKV + (size_t)b * SEQ * 3072 + 2048 + h * 64;
  const int kr = t >> 3;
  const int ksc = (((t & 7) ^ (kr & 7)) << 3);
  const u16* pK1 = Kg + (size_t)kr * 3072 + ksc;
  const int vk = ((t >> 5) << 2) | ((t >> 1) & 3);
  const int vd = (((t >> 3) & 3) << 4) | ((t & 1) << 3);
  const u16* pV1 = Vg + (size_t)vk * 3072 + vd;

  const int sw = (lo & 7) << 4;
  u16* plw = &Pl[w][0];
  const int wbase = ((lo >> 2) << 6) + ((lo & 3) << 4) + (hi << 2);  // P^T write (u16 idx)
  const u16* pt = plw + lo * 4;                                      // P^T tr-read base

  auto stageK = [&](int buf, int it2) {
    const size_t koff = (size_t)it2 * 64 * 3072;
    char* dK = (char*)&Ks[buf][0] + t * 16;
    gload_lds16(pK1 + koff, dK);
    gload_lds16(pK1 + koff + (size_t)32 * 3072, dK + 4096);
  };
  auto stageV = [&](int it2) {
    const size_t koff = (size_t)it2 * 64 * 3072;
    char* dV = (char*)Vs + t * 16;
    gload_lds16(pV1 + koff, dV);
    gload_lds16(pV1 + koff + (size_t)32 * 3072, dV + 4096);
  };

  stageK(0, 0);
  int cur = 0;
  for (int it = 0; it < NT; ++it) {
    __syncthreads();                 // PV(i-1) done everywhere; K(cur) landed
    stageV(it);                      // oldest 2 VMEM ops -> vmcnt(2) targets these
    if (it + 1 < NT) stageK(cur ^ 1, it + 1);

    // QK^T raw scores: S[16q][64k] per wave
    const char* ksb = (const char*)&Ks[cur][0];
    f32x4 sr[4];
    __builtin_amdgcn_s_setprio(1);
#pragma unroll
    for (int fk = 0; fk < 4; ++fk) {
      const char* krow = ksb + (fk * 16 + lo) * 128;
      bf16x8 kb0 = *(const bf16x8*)(krow + ((hi << 4) ^ sw));
      bf16x8 kb1 = *(const bf16x8*)(krow + ((64 + (hi << 4)) ^ sw));
      f32x4 s4 = {};
      s4 = __builtin_amdgcn_mfma_f32_16x16x32_bf16(qf0, kb0, s4, 0, 0, 0);
      sr[fk] = __builtin_amdgcn_mfma_f32_16x16x32_bf16(qf1, kb1, s4, 0, 0, 0);
    }
    __builtin_amdgcn_s_setprio(0);

    // per-lane tile max (scaled into exp2 domain)
    float tm[4];
#pragma unroll
    for (int r = 0; r < 4; ++r)
      tm[r] = fmaxf(fmaxf(sr[0][r], sr[1][r]), fmaxf(sr[2][r], sr[3][r])) * C_SC;

    // defer-max: rescale only if some row grew past mr + 8
    bool ok = (tm[0] <= mr[0] + 8.f) & (tm[1] <= mr[1] + 8.f)
            & (tm[2] <= mr[2] + 8.f) & (tm[3] <= mr[3] + 8.f);
    if (!__all(ok ? 1 : 0)) {
#pragma unroll
      for (int m = 1; m <= 8; m <<= 1)
#pragma unroll
        for (int r = 0; r < 4; ++r)
          tm[r] = fmaxf(tm[r], __shfl_xor(tm[r], m, 64));
#pragma unroll
      for (int r = 0; r < 4; ++r) {
        float mn = fmaxf(mr[r], tm[r]);
        float corr = EXP2F(mr[r] - mn);
        mr[r] = mn;
        acc[0][r] *= corr; acc[1][r] *= corr; acc[2][r] *= corr; acc[3][r] *= corr;
        accl[r] *= corr;
      }
    }

    // P = exp2(s*c - m), pack pairs via cvt_pk, store to P^T (b64 writes)
    float nm0 = -mr[0], nm1 = -mr[1], nm2 = -mr[2], nm3 = -mr[3];
#pragma unroll
    for (int fk = 0; fk < 4; ++fk) {
      float p0 = EXP2F(fmaf(sr[fk][0], C_SC, nm0));
      float p1 = EXP2F(fmaf(sr[fk][1], C_SC, nm1));
      float p2 = EXP2F(fmaf(sr[fk][2], C_SC, nm2));
      float p3 = EXP2F(fmaf(sr[fk][3], C_SC, nm3));
      uint2 pk;
      asm("v_cvt_pk_bf16_f32 %0, %1, %2" : "=v"(pk.x) : "v"(p0), "v"(p1));
      asm("v_cvt_pk_bf16_f32 %0, %1, %2" : "=v"(pk.y) : "v"(p2), "v"(p3));
      *(uint2*)&plw[wbase + fk * 256] = pk;
    }
    asm volatile("" ::: "memory");   // P stores stay above the barrier/tr-reads

    // V ready: wait OWN V loads (K(i+1) stays in flight), then cross-wave barrier
    if (it + 1 < NT) { asm volatile("s_waitcnt vmcnt(2)" ::: "memory"); }
    else             { asm volatile("s_waitcnt vmcnt(0)" ::: "memory"); }
    __builtin_amdgcn_s_barrier();

    // PV: issue ALL tr-reads (P + V, both kk halves), counted lgkm waits
    const u16* vbase = &Vs[0] + hi * 512 + lo * 4;
    bf16x4 a0[2], a1[2], ta[2][4], tb[2][4];
#pragma unroll
    for (int kk = 0; kk < 2; ++kk) {
      a0[kk] = tr_read_b16(pt + (kk * 8 + hi * 2) * 64);
      a1[kk] = tr_read_b16(pt + (kk * 8 + hi * 2) * 64 + 64);
#pragma unroll
      for (int fd = 0; fd < 4; ++fd) {
        const u16* p0 = vbase + kk * 2048 + fd * 64;
        ta[kk][fd] = tr_read_b16(p0);
        tb[kk][fd] = tr_read_b16(p0 + 256);
      }
    }
    asm volatile("s_waitcnt lgkmcnt(10)" ::: "memory");   // kk0's 10 reads done
    __builtin_amdgcn_sched_barrier(0);
    __builtin_amdgcn_s_setprio(1);
    {
      bf16x8 pa = __builtin_shufflevector(a0[0], a1[0], 0, 1, 2, 3, 4, 5, 6, 7);
      accl = __builtin_amdgcn_mfma_f32_16x16x32_bf16(pa, ones, accl, 0, 0, 0);
#pragma unroll
      for (int fd = 0; fd < 4; ++fd) {
        bf16x8 vb = __builtin_shufflevector(ta[0][fd], tb[0][fd], 0, 1, 2, 3, 4, 5, 6, 7);
        acc[fd] = __builtin_amdgcn_mfma_f32_16x16x32_bf16(pa, vb, acc[fd], 0, 0, 0);
      }
    }
    __builtin_amdgcn_s_setprio(0);
    asm volatile("s_waitcnt lgkmcnt(0)" ::: "memory");
    __builtin_amdgcn_sched_barrier(0);
    __builtin_amdgcn_s_setprio(1);
    {
      bf16x8 pa = __builtin_shufflevector(a0[1], a1[1], 0, 1, 2, 3, 4, 5, 6, 7);
      accl = __builtin_amdgcn_mfma_f32_16x16x32_bf16(pa, ones, accl, 0, 0, 0);
#pragma unroll
      for (int fd = 0; fd < 4; ++fd) {
        bf16x8 vb = __builtin_shufflevector(ta[1][fd], tb[1][fd], 0, 1, 2, 3, 4, 5, 6, 7);
        acc[fd] = __builtin_amdgcn_mfma_f32_16x16x32_bf16(pa, vb, acc[fd], 0, 0, 0);
      }
    }
    __builtin_amdgcn_s_setprio(0);
    cur ^= 1;
  }

  // epilogue: O / l -> Y bf16
  float rinv[4];
#pragma unroll
  for (int r = 0; r < 4; ++r) rinv[r] = __builtin_amdgcn_rcpf(accl[r]);
#pragma unroll
  for (int fd = 0; fd < 4; ++fd)
#pragma unroll
    for (int r = 0; r < 4; ++r) {
      int row = q0 + w * 16 + hi * 4 + r;
      int col = h * 64 + fd * 16 + lo;
      Y[(size_t)(b * SEQ + row) * 1024 + col] = f2bf(acc[fd][r] * rinv[r]);
    }
}

extern "C" void kernel_launch(void* const* d_in, const int* in_sizes, int n_in,
                              void* d_out, int out_size, void* d_ws, size_t ws_size,
                              hipStream_t stream) {
  const float* x     = (const float*)d_in[0];
  const float* freqs = (const float*)d_in[1];
  const float* wq_w  = (const float*)d_in[2];
  const float* wq_b  = (const float*)d_in[3];
  const float* wk_w  = (const float*)d_in[4];
  const float* wk_b  = (const float*)d_in[5];
  const float* wv_w  = (const float*)d_in[6];
  const float* wv_b  = (const float*)d_in[7];
  const float* wo_w  = (const float*)d_in[8];
  const float* wo_b  = (const float*)d_in[9];

  char* ws = (char*)d_ws;
  u16*   Xb    = (u16*)(ws);                       //  8 MB  (4096x1024 bf16)
  u16*   Wqkv  = (u16*)(ws + 8388608);             //  6 MB  (3072x1024 bf16)
  u16*   Wo    = (u16*)(ws + 14680064);            //  2 MB  (1024x1024 bf16)
  float* biasq = (float*)(ws + 16777216);          // 12 KB  (3072 f32)
  u16*   QKV   = (u16*)(ws + 16789504);            // 24 MB  (4096x3072 bf16)
  u16*   Yb    = (u16*)(ws + 41955328);            //  8 MB  (4096x1024 bf16)

  prep_kernel<<<8204, 256, 0, stream>>>(x, wq_w, wk_w, wv_w, wo_w, wq_b, wk_b, wv_b,
                                        Xb, Wqkv, Wo, biasq);
  // QKV projection with fused RoPE on Q,K columns (128x128 tile, 3 blocks/CU)
  gemm_bt<u16, true, 128><<<dim3(32, 24), 256, 0, stream>>>(Xb, Wqkv, biasq, QKV, NTOK, 3072, 1024, freqs);
  // attention (frozen R8 structure)
  attn_kernel<<<dim3(SEQ / 64, 32), 256, 0, stream>>>(QKV, Yb);
  // output projection -> f32 d_out (64x128 tile -> 512 blocks = 2/CU)
  gemm_bt<float, false, 64><<<dim3(64, 8), 256, 0, stream>>>(Yb, Wo, wo_b, (float*)d_out, NTOK, 1024, 1024, nullptr);
}